// Round 1
// baseline (191.899 us; speedup 1.0000x reference)
//
#include <hip/hip_runtime.h>
#include <hip/hip_bf16.h>
#include <cstdint>

#define N_IDE 4096
#define M_U   16384
#define D_DIM 256
#define EPSF  1e-12f

typedef _Float16 f16x8 __attribute__((ext_vector_type(8)));
typedef float    f32x4 __attribute__((ext_vector_type(4)));

// ---- async global->LDS 16B copy. LDS dest = wave-uniform base + lane*16. ----
// Generic->AS3 cast done via uintptr truncation (LLVM lowers flat->LDS
// addrspacecast as a 32-bit truncate; apertures are 2^32-aligned).
__device__ __forceinline__ void gll16(const void* g, void* l) {
  __builtin_amdgcn_global_load_lds(
      (const __attribute__((address_space(1))) void*)(uintptr_t)g,
      (__attribute__((address_space(3))) void*)(uint32_t)(uintptr_t)l,
      16, 0, 0);
}

__device__ __forceinline__ unsigned short f2h_bits(float f) {
  _Float16 h = (_Float16)f;
  return __builtin_bit_cast(unsigned short, h);
}

// ---- Kernel 1: fp32 -> f16 convert + row squared-norms (one wave per row) ----
__global__ __launch_bounds__(256) void k_conv(const float* __restrict__ ide,
                                              const float* __restrict__ u,
                                              unsigned short* __restrict__ Ah,
                                              unsigned short* __restrict__ Bh,
                                              float* __restrict__ x2,
                                              float* __restrict__ y2) {
  int gw = (blockIdx.x * 256 + threadIdx.x) >> 6;   // global wave id = row
  int l  = threadIdx.x & 63;
  const float4* src;
  ushort4* dst;
  float* nrm;
  if (gw < N_IDE) {
    src = (const float4*)(ide + (size_t)gw * D_DIM);
    dst = (ushort4*)(Ah + (size_t)gw * D_DIM);
    nrm = x2 + gw;
  } else {
    int r = gw - N_IDE;
    src = (const float4*)(u + (size_t)r * D_DIM);
    dst = (ushort4*)(Bh + (size_t)r * D_DIM);
    nrm = y2 + r;
  }
  float4 v = src[l];  // 64 lanes x 4 fp32 = 256 elements = one row
  float s = v.x * v.x + v.y * v.y + v.z * v.z + v.w * v.w;
  ushort4 o;
  o.x = f2h_bits(v.x); o.y = f2h_bits(v.y);
  o.z = f2h_bits(v.z); o.w = f2h_bits(v.w);
  dst[l] = o;
#pragma unroll
  for (int m = 1; m <= 32; m <<= 1) s += __shfl_xor(s, m, 64);
  if (l == 0) *nrm = s;
}

// ---- Kernel 2: MFMA GEMM tile 128x128, BK=64, fused sqrt-dist + row-sum ----
// partial[bx][row] = sum over this block's 128 u-columns of dist(row, col)
__global__ __launch_bounds__(256) void k_gemm(const unsigned short* __restrict__ Ah,
                                              const unsigned short* __restrict__ Bh,
                                              const float* __restrict__ x2,
                                              const float* __restrict__ y2,
                                              float* __restrict__ partial) {
  __shared__ __align__(16) unsigned short sA[128 * 64];
  __shared__ __align__(16) unsigned short sB[128 * 64];
  __shared__ float rowsum[256];

  const int t    = threadIdx.x;
  const int w    = t >> 6;
  const int wm   = w >> 1, wn = w & 1;        // 2x2 wave grid, each 64x64
  const int l    = t & 63;
  const int lrow = l & 15;                    // A row / B col / C col
  const int lhi  = l >> 4;                    // k-group for A/B, row-quad for C
  const int bx   = blockIdx.x;                // over M/128 = 128
  const int by   = blockIdx.y;                // over N/128 = 32
  const int scol = (t & 7) * 8;               // staging k-offset (elements)

  f32x4 acc[4][4];
#pragma unroll
  for (int i = 0; i < 4; ++i)
#pragma unroll
    for (int j = 0; j < 4; ++j)
      acc[i][j] = (f32x4){0.f, 0.f, 0.f, 0.f};

  for (int kt = 0; kt < 4; ++kt) {
    // stage A,B tiles (128x64 f16 = 16KB each) via direct-to-LDS 16B copies
#pragma unroll
    for (int c = 0; c < 4; ++c) {
      int row = c * 32 + (t >> 3);
      gll16(Ah + (size_t)(by * 128 + row) * D_DIM + kt * 64 + scol,
            sA + (size_t)(c * 256 + w * 64) * 8);
      gll16(Bh + (size_t)(bx * 128 + row) * D_DIM + kt * 64 + scol,
            sB + (size_t)(c * 256 + w * 64) * 8);
    }
    __syncthreads();

    f16x8 af[4][2], bfr[4][2];
#pragma unroll
    for (int mi = 0; mi < 4; ++mi)
#pragma unroll
      for (int ks = 0; ks < 2; ++ks)
        af[mi][ks] = *(const f16x8*)(sA + (wm * 64 + mi * 16 + lrow) * 64 + ks * 32 + lhi * 8);
#pragma unroll
    for (int ni = 0; ni < 4; ++ni)
#pragma unroll
      for (int ks = 0; ks < 2; ++ks)
        bfr[ni][ks] = *(const f16x8*)(sB + (wn * 64 + ni * 16 + lrow) * 64 + ks * 32 + lhi * 8);

#pragma unroll
    for (int mi = 0; mi < 4; ++mi)
#pragma unroll
      for (int ni = 0; ni < 4; ++ni) {
        acc[mi][ni] = __builtin_amdgcn_mfma_f32_16x16x32_f16(af[mi][0], bfr[ni][0], acc[mi][ni], 0, 0, 0);
        acc[mi][ni] = __builtin_amdgcn_mfma_f32_16x16x32_f16(af[mi][1], bfr[ni][1], acc[mi][ni], 0, 0, 0);
      }
    __syncthreads();
  }

  // ---- epilogue: dist = sqrt(max(x2+y2-2xy,0)+eps), reduce over cols ----
  float y2v[4];
#pragma unroll
  for (int ni = 0; ni < 4; ++ni)
    y2v[ni] = y2[bx * 128 + wn * 64 + ni * 16 + lrow];

#pragma unroll
  for (int mi = 0; mi < 4; ++mi) {
#pragma unroll
    for (int rr = 0; rr < 4; ++rr) {
      int lr = wm * 64 + mi * 16 + lhi * 4 + rr;      // local row in [0,128)
      float x2v = x2[by * 128 + lr];
      float s = 0.f;
#pragma unroll
      for (int ni = 0; ni < 4; ++ni) {
        float d2 = x2v + y2v[ni] - 2.0f * acc[mi][ni][rr];
        d2 = fmaxf(d2, 0.0f);
        s += sqrtf(d2 + EPSF);
      }
      // reduce across the 16 lanes holding this row's 16 cols
      s += __shfl_xor(s, 1, 64);
      s += __shfl_xor(s, 2, 64);
      s += __shfl_xor(s, 4, 64);
      s += __shfl_xor(s, 8, 64);
      if (lrow == 0) rowsum[wn * 128 + lr] = s;
    }
  }
  __syncthreads();
  if (t < 128)
    partial[(size_t)bx * N_IDE + by * 128 + t] = rowsum[t] + rowsum[128 + t];
}

// ---- Kernel 3: d[i] = (1/M) * sum over 128 column-blocks of partial ----
__global__ __launch_bounds__(256) void k_dmean(const float* __restrict__ partial,
                                               float* __restrict__ d) {
  int i = blockIdx.x * 256 + threadIdx.x;
  double s = 0.0;
  for (int cb = 0; cb < 128; ++cb)
    s += (double)partial[(size_t)cb * N_IDE + i];
  d[i] = (float)(s * (1.0 / (double)M_U));
}

// ---- Kernel 4: loss = sum_{i,j} sqrt((d_i-d_j)^2 + eps) ----
__global__ __launch_bounds__(256) void k_loss(const float* __restrict__ d,
                                              float* __restrict__ out) {
  __shared__ float sd[N_IDE];
  __shared__ float wsum[4];
  int t = threadIdx.x;
  for (int k = t; k < N_IDE; k += 256) sd[k] = d[k];
  __syncthreads();
  int tid = blockIdx.x * 256 + t;   // 65536 threads: 16 per i
  int i   = tid >> 4;
  int jl  = tid & 15;
  float di = sd[i];
  float s  = 0.f;
  for (int k = 0; k < 256; ++k) {
    float diff = di - sd[jl + k * 16];
    s += sqrtf(diff * diff + EPSF);
  }
#pragma unroll
  for (int m = 1; m <= 32; m <<= 1) s += __shfl_xor(s, m, 64);
  if ((t & 63) == 0) wsum[t >> 6] = s;
  __syncthreads();
  if (t == 0) atomicAdd(out, wsum[0] + wsum[1] + wsum[2] + wsum[3]);
}

extern "C" void kernel_launch(void* const* d_in, const int* in_sizes, int n_in,
                              void* d_out, int out_size, void* d_ws, size_t ws_size,
                              hipStream_t stream) {
  (void)in_sizes; (void)n_in; (void)out_size; (void)ws_size;
  const float* ide = (const float*)d_in[0];
  const float* u   = (const float*)d_in[1];
  float* out = (float*)d_out;

  char* ws = (char*)d_ws;
  size_t off = 0;
  unsigned short* Ah = (unsigned short*)(ws + off); off += (size_t)N_IDE * D_DIM * 2;  // 2 MB
  unsigned short* Bh = (unsigned short*)(ws + off); off += (size_t)M_U  * D_DIM * 2;   // 8 MB
  float* x2      = (float*)(ws + off); off += (size_t)N_IDE * 4;
  float* y2      = (float*)(ws + off); off += (size_t)M_U * 4;
  float* partial = (float*)(ws + off); off += (size_t)128 * N_IDE * 4;                 // 2 MB
  float* dmean   = (float*)(ws + off); off += (size_t)N_IDE * 4;
  // total ws use ~= 12.1 MB

  hipMemsetAsync(d_out, 0, sizeof(float), stream);
  k_conv<<<(N_IDE + M_U) / 4, 256, 0, stream>>>(ide, u, Ah, Bh, x2, y2);
  k_gemm<<<dim3(M_U / 128, N_IDE / 128), 256, 0, stream>>>(Ah, Bh, x2, y2, partial);
  k_dmean<<<N_IDE / 256, 256, 0, stream>>>(partial, dmean);
  k_loss<<<256, 256, 0, stream>>>(dmean, out);
}

// Round 2
// 142.525 us; speedup vs baseline: 1.3464x; 1.3464x over previous
//
#include <hip/hip_runtime.h>
#include <hip/hip_bf16.h>
#include <cstdint>

#define N_IDE 4096
#define M_U   16384
#define D_DIM 256
#define EPSF  1e-12f
#define INV_M (1.0f / 16384.0f)

typedef _Float16 f16x8 __attribute__((ext_vector_type(8)));
typedef float    f32x4 __attribute__((ext_vector_type(4)));

// ---- async global->LDS 16B copy. LDS dest = wave-uniform base + lane*16. ----
__device__ __forceinline__ void gll16(const void* g, void* l) {
  __builtin_amdgcn_global_load_lds(
      (const __attribute__((address_space(1))) void*)(uintptr_t)g,
      (__attribute__((address_space(3))) void*)(uint32_t)(uintptr_t)l,
      16, 0, 0);
}

__device__ __forceinline__ unsigned short f2h_bits(float f) {
  _Float16 h = (_Float16)f;
  return __builtin_bit_cast(unsigned short, h);
}

// ---- Kernel 1: fp32 -> f16 convert + row squared-norms (one wave per row) ----
__global__ __launch_bounds__(256) void k_conv(const float* __restrict__ ide,
                                              const float* __restrict__ u,
                                              unsigned short* __restrict__ Ah,
                                              unsigned short* __restrict__ Bh,
                                              float* __restrict__ x2,
                                              float* __restrict__ y2) {
  int gw = (blockIdx.x * 256 + threadIdx.x) >> 6;
  int l  = threadIdx.x & 63;
  const float4* src;
  ushort4* dst;
  float* nrm;
  if (gw < N_IDE) {
    src = (const float4*)(ide + (size_t)gw * D_DIM);
    dst = (ushort4*)(Ah + (size_t)gw * D_DIM);
    nrm = x2 + gw;
  } else {
    int r = gw - N_IDE;
    src = (const float4*)(u + (size_t)r * D_DIM);
    dst = (ushort4*)(Bh + (size_t)r * D_DIM);
    nrm = y2 + r;
  }
  float4 v = src[l];
  float s = v.x * v.x + v.y * v.y + v.z * v.z + v.w * v.w;
  ushort4 o;
  o.x = f2h_bits(v.x); o.y = f2h_bits(v.y);
  o.z = f2h_bits(v.z); o.w = f2h_bits(v.w);
  dst[l] = o;
#pragma unroll
  for (int m = 1; m <= 32; m <<= 1) s += __shfl_xor(s, m, 64);
  if (l == 0) *nrm = s;
}

// ---- Kernel 2: persistent-A MFMA GEMM ----
// grid (8, 32): by = 128-row group; bx picks 8 of 64 column-groups (256 cols each).
// LDS: A 128x256 f16 (64KB, staged once) + B double-buffer 2 x (256x64) f16 (2x32KB).
// 16B-chunk XOR swizzle (c ^ (row&7)) applied at staging via the global source
// address (LDS side must stay wave-uniform-base + lane*16 for global_load_lds).
#define SB_ELEMS (256 * 64)
__global__ __launch_bounds__(256, 1) void k_gemm(const unsigned short* __restrict__ Ah,
                                                 const unsigned short* __restrict__ Bh,
                                                 const float* __restrict__ x2,
                                                 const float* __restrict__ y2,
                                                 float* __restrict__ dsum) {
  __shared__ __align__(16) unsigned short sA[128 * 256];      // 64 KB
  __shared__ __align__(16) unsigned short sB[2 * SB_ELEMS];   // 64 KB

  const int t    = threadIdx.x;
  const int w    = t >> 6;
  const int l    = t & 63;
  const int wm   = w >> 1, wn = w & 1;   // wave tile: 64 rows x 128 cols
  const int lrow = l & 15;
  const int lhi  = l >> 4;
  const int bx   = blockIdx.x;           // 0..7
  const int by   = blockIdx.y;           // 0..31

  // ---- stage A (128 rows x 256 K), swizzled ----
#pragma unroll
  for (int i = 0; i < 16; ++i) {
    int L = i * 256 + t;                 // chunk id 0..4095
    int row = L >> 5;
    int p = L & 31;
    int c = (p & 24) | ((p & 7) ^ (row & 7));
    gll16(Ah + (size_t)(by * 128 + row) * D_DIM + c * 8,
          sA + (size_t)(i * 256 + w * 64) * 8);
  }

  // ---- B tile stage helper: (cgi, kt) -> buf ----
  auto stageB = [&](int cgi, int kt, int buf) {
    const unsigned short* src = Bh + (size_t)cgi * 256 * D_DIM + kt * 64;
#pragma unroll
    for (int j = 0; j < 8; ++j) {
      int L = j * 256 + t;               // chunk id 0..2047
      int row = L >> 3;
      int c = (L & 7) ^ (row & 7);
      gll16(src + (size_t)row * D_DIM + c * 8,
            sB + (size_t)(buf * SB_ELEMS) + (size_t)(j * 256 + w * 64) * 8);
    }
  };

  stageB(bx, 0, 0);   // first tile; A also in flight
  __syncthreads();    // barrier drains vmcnt(0): A + B(step 0) ready

  int s = 0;          // flat step = cg*4 + kt, consumes buf s&1
  for (int cg = 0; cg < 8; ++cg) {
    const int cgi = cg * 8 + bx;         // column-group in 0..63

    f32x4 acc[4][8];
#pragma unroll
    for (int mi = 0; mi < 4; ++mi)
#pragma unroll
      for (int ni = 0; ni < 8; ++ni)
        acc[mi][ni] = (f32x4){0.f, 0.f, 0.f, 0.f};

    for (int kt = 0; kt < 4; ++kt) {
      // prefetch next tile into the other buffer
      if (s + 1 < 32)
        stageB(((s + 1) >> 2) * 8 + bx, (s + 1) & 3, (s + 1) & 1);

      // A fragments for this kt (reused across both ni-halves)
      f16x8 af[4][2];
#pragma unroll
      for (int mi = 0; mi < 4; ++mi)
#pragma unroll
        for (int ks = 0; ks < 2; ++ks) {
          int arow = wm * 64 + mi * 16 + lrow;
          int ac   = kt * 8 + (((ks << 2) | lhi) ^ (lrow & 7));
          af[mi][ks] = *(const f16x8*)(sA + (size_t)(arow * 32 + ac) * 8);
        }

      const unsigned short* bbuf = sB + (size_t)(s & 1) * SB_ELEMS;
#pragma unroll
      for (int half = 0; half < 2; ++half) {
        f16x8 bf[4][2];
#pragma unroll
        for (int nj = 0; nj < 4; ++nj)
#pragma unroll
          for (int ks = 0; ks < 2; ++ks) {
            int ni   = half * 4 + nj;
            int brow = wn * 128 + ni * 16 + lrow;
            int bc   = ((ks << 2) | lhi) ^ (lrow & 7);
            bf[nj][ks] = *(const f16x8*)(bbuf + (size_t)(brow * 8 + bc) * 8);
          }
#pragma unroll
        for (int mi = 0; mi < 4; ++mi)
#pragma unroll
          for (int nj = 0; nj < 4; ++nj) {
            int ni = half * 4 + nj;
            acc[mi][ni] = __builtin_amdgcn_mfma_f32_16x16x32_f16(af[mi][0], bf[nj][0], acc[mi][ni], 0, 0, 0);
            acc[mi][ni] = __builtin_amdgcn_mfma_f32_16x16x32_f16(af[mi][1], bf[nj][1], acc[mi][ni], 0, 0, 0);
          }
      }
      __syncthreads();   // drains prefetch; makes buffer swap safe
      ++s;
    }

    // ---- epilogue for this column-group: dist + row partial sums ----
    float yv[8];
#pragma unroll
    for (int ni = 0; ni < 8; ++ni)
      yv[ni] = y2[cgi * 256 + wn * 128 + ni * 16 + lrow];

#pragma unroll
    for (int mi = 0; mi < 4; ++mi) {
#pragma unroll
      for (int rr = 0; rr < 4; ++rr) {
        int grow = by * 128 + wm * 64 + mi * 16 + lhi * 4 + rr;
        float xv = x2[grow];
        float ssum = 0.f;
#pragma unroll
        for (int ni = 0; ni < 8; ++ni) {
          float d2 = xv + yv[ni] - 2.0f * acc[mi][ni][rr];
          d2 = fmaxf(d2, 0.0f);
          ssum += __builtin_amdgcn_sqrtf(d2 + EPSF);
        }
        ssum += __shfl_xor(ssum, 1, 64);
        ssum += __shfl_xor(ssum, 2, 64);
        ssum += __shfl_xor(ssum, 4, 64);
        ssum += __shfl_xor(ssum, 8, 64);
        if (lrow == 0) atomicAdd(&dsum[grow], ssum);
      }
    }
  }
}

// ---- Kernel 3: loss = sum_{i,j} sqrt(((dsum_i-dsum_j)/M)^2 + eps) ----
__global__ __launch_bounds__(256) void k_loss(const float* __restrict__ dsum,
                                              float* __restrict__ out) {
  __shared__ float sd[N_IDE];
  __shared__ float wsum[4];
  int t = threadIdx.x;
  for (int k = t; k < N_IDE; k += 256) sd[k] = dsum[k];
  __syncthreads();
  int tid = blockIdx.x * 256 + t;   // 65536 threads: 16 per i
  int i   = tid >> 4;
  int jl  = tid & 15;
  float di = sd[i];
  float s  = 0.f;
  for (int k = 0; k < 256; ++k) {
    float diff = (di - sd[jl + k * 16]) * INV_M;
    s += __builtin_amdgcn_sqrtf(diff * diff + EPSF);
  }
#pragma unroll
  for (int m = 1; m <= 32; m <<= 1) s += __shfl_xor(s, m, 64);
  if ((t & 63) == 0) wsum[t >> 6] = s;
  __syncthreads();
  if (t == 0) atomicAdd(out, wsum[0] + wsum[1] + wsum[2] + wsum[3]);
}

extern "C" void kernel_launch(void* const* d_in, const int* in_sizes, int n_in,
                              void* d_out, int out_size, void* d_ws, size_t ws_size,
                              hipStream_t stream) {
  (void)in_sizes; (void)n_in; (void)out_size; (void)ws_size;
  const float* ide = (const float*)d_in[0];
  const float* u   = (const float*)d_in[1];
  float* out = (float*)d_out;

  char* ws = (char*)d_ws;
  size_t off = 0;
  unsigned short* Ah = (unsigned short*)(ws + off); off += (size_t)N_IDE * D_DIM * 2;  // 2 MB
  unsigned short* Bh = (unsigned short*)(ws + off); off += (size_t)M_U  * D_DIM * 2;   // 8 MB
  float* x2   = (float*)(ws + off); off += (size_t)N_IDE * 4;
  float* y2   = (float*)(ws + off); off += (size_t)M_U * 4;
  float* dsum = (float*)(ws + off); off += (size_t)N_IDE * 4;

  hipMemsetAsync(d_out, 0, sizeof(float), stream);
  hipMemsetAsync(dsum, 0, (size_t)N_IDE * 4, stream);
  k_conv<<<(N_IDE + M_U) / 4, 256, 0, stream>>>(ide, u, Ah, Bh, x2, y2);
  k_gemm<<<dim3(8, 32), 256, 0, stream>>>(Ah, Bh, x2, y2, dsum);
  k_loss<<<256, 256, 0, stream>>>(dsum, out);
}

// Round 3
// 127.975 us; speedup vs baseline: 1.4995x; 1.1137x over previous
//
#include <hip/hip_runtime.h>
#include <hip/hip_bf16.h>
#include <cstdint>

#define N_IDE 4096
#define M_U   16384
#define D_DIM 256
#define EPSF  1e-12f
#define INV_M (1.0f / 16384.0f)

#define CGC   512                 // columns per column-group tile
#define BK    32                  // K per step
#define SB_ELEMS (CGC * BK)       // 16384 f16 = 32 KB

typedef _Float16 f16x8 __attribute__((ext_vector_type(8)));
typedef float    f32x4 __attribute__((ext_vector_type(4)));

// ---- async global->LDS 16B copy. LDS dest = wave-uniform base + lane*16. ----
__device__ __forceinline__ void gll16(const void* g, void* l) {
  __builtin_amdgcn_global_load_lds(
      (const __attribute__((address_space(1))) void*)(uintptr_t)g,
      (__attribute__((address_space(3))) void*)(uint32_t)(uintptr_t)l,
      16, 0, 0);
}

__device__ __forceinline__ unsigned short f2h_bits(float f) {
  _Float16 h = (_Float16)f;
  return __builtin_bit_cast(unsigned short, h);
}

// ---- Kernel 1: fp32 -> f16 convert + row squared-norms (one wave per row) ----
__global__ __launch_bounds__(256) void k_conv(const float* __restrict__ ide,
                                              const float* __restrict__ u,
                                              unsigned short* __restrict__ Ah,
                                              unsigned short* __restrict__ Bh,
                                              float* __restrict__ x2,
                                              float* __restrict__ y2) {
  int gw = (blockIdx.x * 256 + threadIdx.x) >> 6;
  int l  = threadIdx.x & 63;
  const float4* src;
  ushort4* dst;
  float* nrm;
  if (gw < N_IDE) {
    src = (const float4*)(ide + (size_t)gw * D_DIM);
    dst = (ushort4*)(Ah + (size_t)gw * D_DIM);
    nrm = x2 + gw;
  } else {
    int r = gw - N_IDE;
    src = (const float4*)(u + (size_t)r * D_DIM);
    dst = (ushort4*)(Bh + (size_t)r * D_DIM);
    nrm = y2 + r;
  }
  float4 v = src[l];
  float s = v.x * v.x + v.y * v.y + v.z * v.z + v.w * v.w;
  ushort4 o;
  o.x = f2h_bits(v.x); o.y = f2h_bits(v.y);
  o.z = f2h_bits(v.z); o.w = f2h_bits(v.w);
  dst[l] = o;
#pragma unroll
  for (int m = 1; m <= 32; m <<= 1) s += __shfl_xor(s, m, 64);
  if (l == 0) *nrm = s;
}

// ---- Kernel 2: persistent-A MFMA GEMM, 512 threads (8 waves, 2/SIMD) ----
// grid (8, 32): by = 128-row group; bx picks 4 of 32 column-groups (512 cols).
// LDS: A 128x256 f16 (64KB, swizzled, staged once)
//    + B double-buffer 2 x (512 cols x 32 K) f16 (2x32KB, natural layout:
//      64B row pitch makes fragment wave-reads contiguous 1KB -> conflict-free)
// Steps: s = cg*8 + kt, cg in 0..3, kt in 0..7. One-step-ahead B prefetch.
// Output: partial[bx][grow] = sum of dist over this block's 2048 columns.
__global__ __launch_bounds__(512, 2) void k_gemm(const unsigned short* __restrict__ Ah,
                                                 const unsigned short* __restrict__ Bh,
                                                 const float* __restrict__ x2,
                                                 const float* __restrict__ y2,
                                                 float* __restrict__ partial) {
  __shared__ __align__(16) unsigned short sA[128 * 256];      // 64 KB
  __shared__ __align__(16) unsigned short sB[2 * SB_ELEMS];   // 64 KB
  __shared__ float rowacc[4][128];                            // per-wn slices

  const int t    = threadIdx.x;
  const int w    = t >> 6;
  const int l    = t & 63;
  const int wm   = w >> 2, wn = w & 3;   // 2x4 wave grid; wave tile 64x128
  const int lrow = l & 15;
  const int lhi  = l >> 4;
  const int bx   = blockIdx.x;           // 0..7
  const int by   = blockIdx.y;           // 0..31

  rowacc[t >> 7][t & 127] = 0.f;         // 512 threads cover 4x128 exactly

  // ---- stage A (128 rows x 256 K), XOR-swizzled in 16B chunks ----
#pragma unroll
  for (int i = 0; i < 8; ++i) {
    int L = i * 512 + t;                 // chunk id 0..4095
    int row = L >> 5;
    int p = L & 31;
    int c = (p & 24) | ((p & 7) ^ (row & 7));
    gll16(Ah + (size_t)(by * 128 + row) * D_DIM + c * 8,
          sA + (size_t)(i * 512 + w * 64) * 8);
  }

  // ---- B tile stage: flat step s -> buf s&1 (natural layout, no swizzle) ----
  auto stageB = [&](int s) {
    const int cgi = (s >> 3) * 8 + bx;   // column-group 0..31
    const int kt  = s & 7;
    const unsigned short* src = Bh + (size_t)cgi * CGC * D_DIM + kt * BK;
    unsigned short* dstb = sB + (size_t)(s & 1) * SB_ELEMS;
#pragma unroll
    for (int j = 0; j < 4; ++j) {
      int L = j * 512 + t;               // chunk id 0..2047
      int row = L >> 2;                  // B row (= C column) 0..511
      int c = L & 3;                     // 16B chunk within 64B row
      gll16(src + (size_t)row * D_DIM + c * 8,
            dstb + (size_t)(j * 512 + w * 64) * 8);
    }
  };

  // x2 for this wave's rows, loaded once (rr 0..3 contiguous -> float4)
  float4 x2v[4];
#pragma unroll
  for (int mi = 0; mi < 4; ++mi)
    x2v[mi] = *(const float4*)&x2[by * 128 + wm * 64 + mi * 16 + lhi * 4];

  stageB(0);
  __syncthreads();    // barrier drains vmcnt(0): A + B(step 0) ready

  for (int cg = 0; cg < 4; ++cg) {
    const int cgi = cg * 8 + bx;

    f32x4 acc[4][8];
#pragma unroll
    for (int mi = 0; mi < 4; ++mi)
#pragma unroll
      for (int ni = 0; ni < 8; ++ni)
        acc[mi][ni] = (f32x4){0.f, 0.f, 0.f, 0.f};

    for (int kt = 0; kt < 8; ++kt) {
      const int s = cg * 8 + kt;
      if (s + 1 < 32) stageB(s + 1);     // prefetch into other buffer

      // A fragments: logical chunk kt*4+lhi, physical = swizzled
      f16x8 af[4];
#pragma unroll
      for (int mi = 0; mi < 4; ++mi) {
        int arow = wm * 64 + mi * 16 + lrow;
        int lc   = kt * 4 + lhi;
        int pc   = (lc & 24) | ((lc & 7) ^ (lrow & 7));
        af[mi] = *(const f16x8*)(sA + (size_t)arow * 256 + pc * 8);
      }

      const unsigned short* bbuf = sB + (size_t)(s & 1) * SB_ELEMS;
#pragma unroll
      for (int half = 0; half < 2; ++half) {
        f16x8 bf[4];
#pragma unroll
        for (int nj = 0; nj < 4; ++nj) {
          int brow = wn * 128 + (half * 4 + nj) * 16 + lrow;
          bf[nj] = *(const f16x8*)(bbuf + (size_t)brow * BK + lhi * 8);
        }
#pragma unroll
        for (int mi = 0; mi < 4; ++mi)
#pragma unroll
          for (int nj = 0; nj < 4; ++nj)
            acc[mi][half * 4 + nj] =
                __builtin_amdgcn_mfma_f32_16x16x32_f16(af[mi], bf[nj],
                                                       acc[mi][half * 4 + nj], 0, 0, 0);
      }
      __syncthreads();   // prefetch drained; buffer swap safe
    }

    // ---- epilogue: dist + row partial sums into this wave's rowacc slice ----
    float yv[8];
#pragma unroll
    for (int ni = 0; ni < 8; ++ni)
      yv[ni] = y2[cgi * CGC + wn * 128 + ni * 16 + lrow];

#pragma unroll
    for (int mi = 0; mi < 4; ++mi) {
      float xr[4] = {x2v[mi].x, x2v[mi].y, x2v[mi].z, x2v[mi].w};
#pragma unroll
      for (int rr = 0; rr < 4; ++rr) {
        float ssum = 0.f;
#pragma unroll
        for (int ni = 0; ni < 8; ++ni) {
          float d2 = xr[rr] + yv[ni] - 2.0f * acc[mi][ni][rr];
          d2 = fmaxf(d2, 0.0f);
          ssum += __builtin_amdgcn_sqrtf(d2 + EPSF);
        }
        ssum += __shfl_xor(ssum, 1, 64);
        ssum += __shfl_xor(ssum, 2, 64);
        ssum += __shfl_xor(ssum, 4, 64);
        ssum += __shfl_xor(ssum, 8, 64);
        if (lrow == 0)
          rowacc[wn][wm * 64 + mi * 16 + lhi * 4 + rr] += ssum;  // wave-private slice
      }
    }
  }

  __syncthreads();
  if (t < 128)
    partial[(size_t)bx * N_IDE + by * 128 + t] =
        rowacc[0][t] + rowacc[1][t] + rowacc[2][t] + rowacc[3][t];
}

// ---- Kernel 3: loss = sum_{i,j} sqrt(((d_i-d_j))^2 + eps), d from partials ----
__global__ __launch_bounds__(256) void k_loss(const float* __restrict__ partial,
                                              float* __restrict__ out) {
  __shared__ float sd[N_IDE];
  __shared__ float wsum[4];
  int t = threadIdx.x;
  for (int k = t; k < N_IDE; k += 256) {
    float s = 0.f;
#pragma unroll
    for (int b = 0; b < 8; ++b) s += partial[(size_t)b * N_IDE + k];
    sd[k] = s;
  }
  __syncthreads();
  int tid = blockIdx.x * 256 + t;   // 65536 threads: 16 per i
  int i   = tid >> 4;
  int jl  = tid & 15;
  float di = sd[i];
  float s  = 0.f;
  for (int k = 0; k < 256; ++k) {
    float diff = (di - sd[jl + k * 16]) * INV_M;
    s += __builtin_amdgcn_sqrtf(diff * diff + EPSF);
  }
#pragma unroll
  for (int m = 1; m <= 32; m <<= 1) s += __shfl_xor(s, m, 64);
  if ((t & 63) == 0) wsum[t >> 6] = s;
  __syncthreads();
  if (t == 0) atomicAdd(out, wsum[0] + wsum[1] + wsum[2] + wsum[3]);
}

extern "C" void kernel_launch(void* const* d_in, const int* in_sizes, int n_in,
                              void* d_out, int out_size, void* d_ws, size_t ws_size,
                              hipStream_t stream) {
  (void)in_sizes; (void)n_in; (void)out_size; (void)ws_size;
  const float* ide = (const float*)d_in[0];
  const float* u   = (const float*)d_in[1];
  float* out = (float*)d_out;

  char* ws = (char*)d_ws;
  size_t off = 0;
  unsigned short* Ah = (unsigned short*)(ws + off); off += (size_t)N_IDE * D_DIM * 2;  // 2 MB
  unsigned short* Bh = (unsigned short*)(ws + off); off += (size_t)M_U  * D_DIM * 2;   // 8 MB
  float* x2      = (float*)(ws + off); off += (size_t)N_IDE * 4;
  float* y2      = (float*)(ws + off); off += (size_t)M_U * 4;
  float* partial = (float*)(ws + off); off += (size_t)8 * N_IDE * 4;                   // 128 KB

  hipMemsetAsync(d_out, 0, sizeof(float), stream);
  k_conv<<<(N_IDE + M_U) / 4, 256, 0, stream>>>(ide, u, Ah, Bh, x2, y2);
  k_gemm<<<dim3(8, 32), 512, 0, stream>>>(Ah, Bh, x2, y2, partial);
  k_loss<<<256, 256, 0, stream>>>(partial, out);
}